// Round 1
// baseline (12266.824 us; speedup 1.0000x reference)
//
#include <hip/hip_runtime.h>

// LightGCN propagation on MI355X (gfx950).
// N = 150000 nodes, D = 64, NNZ = 4.8M COO edges, 3 SpMM layers, mean of 4 stages.
// Baseline strategy: atomic COO SpMM (16 threads/edge, float4 lanes), accumulator in d_out.
// Working set (~134 MB) fits Infinity Cache -> gathers/scatters should be L3-resident.

#define NUSERS 100000
#define NITEMS 50000
#define NTOT   150000
#define DIM    64
#define NNZ_E  4800000

constexpr int TOT4 = NTOT * DIM / 4;    // 2,400,000 float4 elements
constexpr int USR4 = NUSERS * DIM / 4;  // 1,600,000 float4 elements

__global__ void init_kernel(const float* __restrict__ user, const float* __restrict__ item,
                            float4* __restrict__ x, float4* __restrict__ acc) {
    int i = blockIdx.x * blockDim.x + threadIdx.x;
    if (i >= TOT4) return;
    float4 v = (i < USR4) ? ((const float4*)user)[i]
                          : ((const float4*)item)[i - USR4];
    x[i]   = v;
    acc[i] = v;
}

__global__ void zero_kernel(float4* __restrict__ y) {
    int i = blockIdx.x * blockDim.x + threadIdx.x;
    if (i >= TOT4) return;
    y[i] = make_float4(0.f, 0.f, 0.f, 0.f);
}

// One edge handled by 16 consecutive threads; thread d4 covers components [4*d4, 4*d4+4).
// Gather x[col] as float4 (wave-coalesced 256 B per edge), scatter via 4 fp32 atomics.
__global__ void spmm_atomic(const int* __restrict__ rows, const int* __restrict__ cols,
                            const float* __restrict__ vals,
                            const float* __restrict__ x, float* __restrict__ y) {
    long long t = (long long)blockIdx.x * blockDim.x + threadIdx.x;
    int e = (int)(t >> 4);
    if (e >= NNZ_E) return;
    int d4 = (int)(t & 15);
    int r = rows[e];
    int c = cols[e];
    float v = vals[e];
    float4 xv = ((const float4*)x)[(size_t)c * (DIM / 4) + d4];
    float* yp = y + (size_t)r * DIM + (size_t)d4 * 4;
    atomicAdd(yp + 0, v * xv.x);
    atomicAdd(yp + 1, v * xv.y);
    atomicAdd(yp + 2, v * xv.z);
    atomicAdd(yp + 3, v * xv.w);
}

__global__ void acc_add(const float4* __restrict__ y, float4* __restrict__ acc) {
    int i = blockIdx.x * blockDim.x + threadIdx.x;
    if (i >= TOT4) return;
    float4 a = acc[i];
    float4 b = y[i];
    a.x += b.x; a.y += b.y; a.z += b.z; a.w += b.w;
    acc[i] = a;
}

__global__ void acc_add_scale(const float4* __restrict__ y, float4* __restrict__ acc) {
    int i = blockIdx.x * blockDim.x + threadIdx.x;
    if (i >= TOT4) return;
    float4 a = acc[i];
    float4 b = y[i];
    a.x = (a.x + b.x) * 0.25f;
    a.y = (a.y + b.y) * 0.25f;
    a.z = (a.z + b.z) * 0.25f;
    a.w = (a.w + b.w) * 0.25f;
    acc[i] = a;
}

extern "C" void kernel_launch(void* const* d_in, const int* in_sizes, int n_in,
                              void* d_out, int out_size, void* d_ws, size_t ws_size,
                              hipStream_t stream) {
    const float* user = (const float*)d_in[0];
    const float* item = (const float*)d_in[1];
    const float* vals = (const float*)d_in[2];
    const int*   rows = (const int*)d_in[3];
    const int*   cols = (const int*)d_in[4];
    float* out = (float*)d_out;

    float* x = (float*)d_ws;                       // 38.4 MB
    float* y = x + (size_t)NTOT * DIM;             // 38.4 MB (ws total: 76.8 MB)

    const int blk = 256;
    const int gElem = (TOT4 + blk - 1) / blk;                              // 9375 blocks
    const int gSpmm = (int)(((long long)NNZ_E * 16 + blk - 1) / blk);      // 300000 blocks

    // acc (d_out) = x0 = concat(user_emb, item_emb); x = x0
    init_kernel<<<gElem, blk, 0, stream>>>(user, item, (float4*)x, (float4*)out);

    float* cur = x;
    float* nxt = y;
    for (int l = 0; l < 3; ++l) {
        zero_kernel<<<gElem, blk, 0, stream>>>((float4*)nxt);
        spmm_atomic<<<gSpmm, blk, 0, stream>>>(rows, cols, vals, cur, nxt);
        if (l < 2) {
            acc_add<<<gElem, blk, 0, stream>>>((const float4*)nxt, (float4*)out);
        } else {
            // final layer: acc = (acc + y) / 4  (the stage-mean)
            acc_add_scale<<<gElem, blk, 0, stream>>>((const float4*)nxt, (float4*)out);
        }
        float* tmp = cur; cur = nxt; nxt = tmp;
    }
}

// Round 2
// 1739.313 us; speedup vs baseline: 7.0527x; 7.0527x over previous
//
#include <hip/hip_runtime.h>

// LightGCN on MI355X (gfx950). Round 2: de-atomized SpMM via per-call CSR build.
// R1 evidence: spmm_atomic 4.04 ms/layer, VALUBusy 1.25%, WRITE_SIZE 4.8 GB/layer
// -> atomic-op-throughput bound (~76G atomics/s). Fix: counting-sort edges into CSR
// (histogram + scan + scatter, ~4.8M int atomics total), then wave-per-row SpMM with
// register accumulation: zero fp32 atomics, one coalesced 256B store per row.

#define NUSERS 100000
#define NITEMS 50000
#define NTOT   150000
#define DIM    64
#define NNZ_E  4800000

constexpr int TOT4 = NTOT * DIM / 4;    // 2,400,000 float4
constexpr int USR4 = NUSERS * DIM / 4;  // 1,600,000 float4
constexpr int SCAN_T = 1024;
constexpr int CHUNK = (NTOT + SCAN_T - 1) / SCAN_T;  // 147

__global__ void init_kernel(const float* __restrict__ user, const float* __restrict__ item,
                            float4* __restrict__ x, float4* __restrict__ acc) {
    int i = blockIdx.x * blockDim.x + threadIdx.x;
    if (i >= TOT4) return;
    float4 v = (i < USR4) ? ((const float4*)user)[i]
                          : ((const float4*)item)[i - USR4];
    x[i]   = v;
    acc[i] = v;
}

__global__ void zero_int(int* __restrict__ p, int n) {
    int i = blockIdx.x * blockDim.x + threadIdx.x;
    if (i < n) p[i] = 0;
}

__global__ void hist_kernel(const int* __restrict__ rows, int* __restrict__ cnt) {
    int e = blockIdx.x * blockDim.x + threadIdx.x;
    if (e < NNZ_E) atomicAdd(&cnt[rows[e]], 1);
}

// Single-block exclusive scan over cnt[NTOT] -> rowptr[NTOT+1], cursor[NTOT].
// 1024 threads, each serially scans a 147-element chunk; Hillis-Steele over chunk totals.
__global__ void scan_kernel(const int* __restrict__ cnt, int* __restrict__ rowptr,
                            int* __restrict__ cursor) {
    __shared__ int tmp[SCAN_T];
    int tid = threadIdx.x;
    int begin = tid * CHUNK;
    int end = begin + CHUNK; if (end > NTOT) end = NTOT;
    int s = 0;
    if (begin < NTOT) for (int i = begin; i < end; ++i) s += cnt[i];
    tmp[tid] = s;
    __syncthreads();
    for (int ofs = 1; ofs < SCAN_T; ofs <<= 1) {
        int v = (tid >= ofs) ? tmp[tid - ofs] : 0;
        __syncthreads();
        tmp[tid] += v;
        __syncthreads();
    }
    int off = tmp[tid] - s;   // exclusive prefix of this chunk
    if (begin < NTOT) {
        int run = off;
        for (int i = begin; i < end; ++i) {
            int c = cnt[i];
            rowptr[i] = run;
            cursor[i] = run;
            run += c;
        }
    }
    if (tid == SCAN_T - 1) rowptr[NTOT] = tmp[tid];  // total = NNZ
}

__global__ void scatter_kernel(const int* __restrict__ rows, const int* __restrict__ cols,
                               const float* __restrict__ vals,
                               int* __restrict__ cursor,
                               int* __restrict__ scol, float* __restrict__ sval) {
    int e = blockIdx.x * blockDim.x + threadIdx.x;
    if (e >= NNZ_E) return;
    int r = rows[e];
    int p = atomicAdd(&cursor[r], 1);
    scol[p] = cols[e];
    sval[p] = vals[e];
}

// One wave per row. Lane d accumulates component d across the row's edges.
// col/val are wave-uniform loads (L1 broadcast); gather is a coalesced 256B read.
__global__ void spmm_csr(const int* __restrict__ rowptr, const int* __restrict__ scol,
                         const float* __restrict__ sval,
                         const float* __restrict__ x, float* __restrict__ y,
                         float* __restrict__ acc, int last) {
    int wave = blockIdx.x * (blockDim.x >> 6) + (threadIdx.x >> 6);
    if (wave >= NTOT) return;
    int lane = threadIdx.x & 63;
    int start = rowptr[wave];
    int end   = rowptr[wave + 1];
    float sum = 0.f;
    int i = start;
    for (; i + 1 < end; i += 2) {
        int   c0 = scol[i],     c1 = scol[i + 1];
        float v0 = sval[i],     v1 = sval[i + 1];
        float x0 = x[(size_t)c0 * DIM + lane];
        float x1 = x[(size_t)c1 * DIM + lane];
        sum += v0 * x0;
        sum += v1 * x1;
    }
    if (i < end) sum += sval[i] * x[(size_t)scol[i] * DIM + lane];
    size_t o = (size_t)wave * DIM + lane;
    if (last) {
        acc[o] = (acc[o] + sum) * 0.25f;
    } else {
        y[o] = sum;
        acc[o] += sum;
    }
}

extern "C" void kernel_launch(void* const* d_in, const int* in_sizes, int n_in,
                              void* d_out, int out_size, void* d_ws, size_t ws_size,
                              hipStream_t stream) {
    const float* user = (const float*)d_in[0];
    const float* item = (const float*)d_in[1];
    const float* vals = (const float*)d_in[2];
    const int*   rows = (const int*)d_in[3];
    const int*   cols = (const int*)d_in[4];
    float* out = (float*)d_out;

    // Workspace layout (bytes): x 38.4M | y 38.4M | scol 19.2M | sval 19.2M |
    // cnt 0.6M | rowptr 0.6M | cursor 0.6M   (total ~116.6 MB)
    char* w = (char*)d_ws;
    float* x      = (float*)w;                 w += (size_t)NTOT * DIM * 4;
    float* y      = (float*)w;                 w += (size_t)NTOT * DIM * 4;
    int*   scol   = (int*)w;                   w += (size_t)NNZ_E * 4;
    float* sval   = (float*)w;                 w += (size_t)NNZ_E * 4;
    int*   cnt    = (int*)w;                   w += (size_t)NTOT * 4;
    int*   rowptr = (int*)w;                   w += (size_t)(NTOT + 1) * 4;
    int*   cursor = (int*)w;

    const int blk = 256;
    const int gElem = (TOT4 + blk - 1) / blk;          // 9375
    const int gEdge = (NNZ_E + blk - 1) / blk;         // 18750
    const int gCnt  = (NTOT + blk - 1) / blk;          // 586
    const int gRow  = (NTOT + (blk / 64) - 1) / (blk / 64);  // 37500 blocks, 4 waves each

    // ---- CSR build (once per call; ws is re-poisoned every call) ----
    zero_int<<<gCnt, blk, 0, stream>>>(cnt, NTOT);
    hist_kernel<<<gEdge, blk, 0, stream>>>(rows, cnt);
    scan_kernel<<<1, SCAN_T, 0, stream>>>(cnt, rowptr, cursor);
    scatter_kernel<<<gEdge, blk, 0, stream>>>(rows, cols, vals, cursor, scol, sval);

    // ---- acc = x0; x = x0 ----
    init_kernel<<<gElem, blk, 0, stream>>>(user, item, (float4*)x, (float4*)out);

    // ---- 3 propagation layers, mean fused into acc ----
    float* cur = x;
    float* nxt = y;
    for (int l = 0; l < 3; ++l) {
        spmm_csr<<<gRow, blk, 0, stream>>>(rowptr, scol, sval, cur, nxt, out, l == 2);
        float* t = cur; cur = nxt; nxt = t;
    }
}

// Round 3
// 1321.209 us; speedup vs baseline: 9.2845x; 1.3165x over previous
//
#include <hip/hip_runtime.h>

// LightGCN on MI355X (gfx950). Round 3.
// R2 evidence: scatter 346us with WRITE_SIZE 441MB (line-granularity random writes,
// 2 arrays); spmm ~330us/layer, bound by ~1.38GB/layer traffic dominated by the
// 4.8M x 256B fp32 gather. Changes: (1) bf16 layer storage halves gather bytes,
// (2) interleaved int2 (col,val) edge array halves scattered lines + single 8B
// wave-uniform edge load, (3) defer the stage-mean to one final fused pass (kills
// 3x 77MB fp32 acc RMW), (4) 4-way unrolled spmm with scalar-forced edge indices.

#define NUSERS 100000
#define NITEMS 50000
#define NTOT   150000
#define DIM    64
#define NNZ_E  4800000

constexpr int TOT4 = NTOT * DIM / 4;    // 2,400,000 (float4 / ushort4 granules)
constexpr int USR4 = NUSERS * DIM / 4;  // 1,600,000
constexpr int SCAN_T = 1024;
constexpr int CHUNK = (NTOT + SCAN_T - 1) / SCAN_T;  // 147

__device__ __forceinline__ float bdec(unsigned short u) {
    union { unsigned u32; float f; } t; t.u32 = (unsigned)u << 16; return t.f;
}
__device__ __forceinline__ unsigned short benc(float f) {
    union { float f; unsigned u; } t; t.f = f;
    unsigned r = t.u + 0x7FFFu + ((t.u >> 16) & 1u);   // round-to-nearest-even
    return (unsigned short)(r >> 16);
}

__global__ void zero_int(int* __restrict__ p, int n) {
    int i = blockIdx.x * blockDim.x + threadIdx.x;
    if (i < n) p[i] = 0;
}

__global__ void hist_kernel(const int* __restrict__ rows, int* __restrict__ cnt) {
    int e = blockIdx.x * blockDim.x + threadIdx.x;
    if (e < NNZ_E) atomicAdd(&cnt[rows[e]], 1);
}

// Single-block exclusive scan: cnt[NTOT] -> rowptr[NTOT+1], cursor[NTOT].
__global__ void scan_kernel(const int* __restrict__ cnt, int* __restrict__ rowptr,
                            int* __restrict__ cursor) {
    __shared__ int tmp[SCAN_T];
    int tid = threadIdx.x;
    int begin = tid * CHUNK;
    int end = begin + CHUNK; if (end > NTOT) end = NTOT;
    int s = 0;
    if (begin < NTOT) for (int i = begin; i < end; ++i) s += cnt[i];
    tmp[tid] = s;
    __syncthreads();
    for (int ofs = 1; ofs < SCAN_T; ofs <<= 1) {
        int v = (tid >= ofs) ? tmp[tid - ofs] : 0;
        __syncthreads();
        tmp[tid] += v;
        __syncthreads();
    }
    int off = tmp[tid] - s;
    if (begin < NTOT) {
        int run = off;
        for (int i = begin; i < end; ++i) {
            int c = cnt[i];
            rowptr[i] = run;
            cursor[i] = run;
            run += c;
        }
    }
    if (tid == SCAN_T - 1) rowptr[NTOT] = tmp[tid];
}

__global__ void scatter_kernel(const int* __restrict__ rows, const int* __restrict__ cols,
                               const float* __restrict__ vals,
                               int* __restrict__ cursor, int2* __restrict__ edges) {
    int e = blockIdx.x * blockDim.x + threadIdx.x;
    if (e >= NNZ_E) return;
    int r = rows[e];
    int p = atomicAdd(&cursor[r], 1);
    edges[p] = make_int2(cols[e], __float_as_int(vals[e]));
}

// x0h = bf16(concat(user, item))
__global__ void convert_kernel(const float* __restrict__ user, const float* __restrict__ item,
                               ushort4* __restrict__ xh) {
    int i = blockIdx.x * blockDim.x + threadIdx.x;
    if (i >= TOT4) return;
    float4 v = (i < USR4) ? ((const float4*)user)[i]
                          : ((const float4*)item)[i - USR4];
    ushort4 o;
    o.x = benc(v.x); o.y = benc(v.y); o.z = benc(v.z); o.w = benc(v.w);
    xh[i] = o;
}

// One wave per row; lane d owns component d. 4-way unrolled, scalar-forced edge
// indices (wave-uniform 8B edge loads), bf16 gather (128B/wave coalesced).
__global__ void spmm_bf16(const int* __restrict__ rowptr, const int2* __restrict__ edges,
                          const unsigned short* __restrict__ xh,
                          unsigned short* __restrict__ yh) {
    int row = blockIdx.x * (blockDim.x >> 6) + (threadIdx.x >> 6);
    if (row >= NTOT) return;
    int lane = threadIdx.x & 63;
    int start = __builtin_amdgcn_readfirstlane(rowptr[row]);
    int end   = __builtin_amdgcn_readfirstlane(rowptr[row + 1]);
    float s0 = 0.f, s1 = 0.f, s2 = 0.f, s3 = 0.f;
    int i = start;
    for (; i + 3 < end; i += 4) {
        int2 e0 = edges[i], e1 = edges[i + 1], e2 = edges[i + 2], e3 = edges[i + 3];
        s0 += __int_as_float(e0.y) * bdec(xh[(size_t)e0.x * DIM + lane]);
        s1 += __int_as_float(e1.y) * bdec(xh[(size_t)e1.x * DIM + lane]);
        s2 += __int_as_float(e2.y) * bdec(xh[(size_t)e2.x * DIM + lane]);
        s3 += __int_as_float(e3.y) * bdec(xh[(size_t)e3.x * DIM + lane]);
    }
    for (; i < end; ++i)
        s0 += __int_as_float(edges[i].y) * bdec(xh[(size_t)edges[i].x * DIM + lane]);
    yh[(size_t)row * DIM + lane] = benc(s0 + s1 + s2 + s3);
}

// out = 0.25 * (x0 + y1 + y2 + y3)
__global__ void final_kernel(const float* __restrict__ user, const float* __restrict__ item,
                             const ushort4* __restrict__ y1, const ushort4* __restrict__ y2,
                             const ushort4* __restrict__ y3, float4* __restrict__ out) {
    int i = blockIdx.x * blockDim.x + threadIdx.x;
    if (i >= TOT4) return;
    float4 v = (i < USR4) ? ((const float4*)user)[i]
                          : ((const float4*)item)[i - USR4];
    ushort4 a = y1[i], b = y2[i], c = y3[i];
    float4 o;
    o.x = 0.25f * (v.x + bdec(a.x) + bdec(b.x) + bdec(c.x));
    o.y = 0.25f * (v.y + bdec(a.y) + bdec(b.y) + bdec(c.y));
    o.z = 0.25f * (v.z + bdec(a.z) + bdec(b.z) + bdec(c.z));
    o.w = 0.25f * (v.w + bdec(a.w) + bdec(b.w) + bdec(c.w));
    out[i] = o;
}

extern "C" void kernel_launch(void* const* d_in, const int* in_sizes, int n_in,
                              void* d_out, int out_size, void* d_ws, size_t ws_size,
                              hipStream_t stream) {
    const float* user = (const float*)d_in[0];
    const float* item = (const float*)d_in[1];
    const float* vals = (const float*)d_in[2];
    const int*   rows = (const int*)d_in[3];
    const int*   cols = (const int*)d_in[4];
    float* out = (float*)d_out;

    // ws layout (117.0 MB total, same as R2's accepted layout):
    // edges 38.4M | x0h 19.2M | y1h 19.2M | y2h 19.2M | y3h 19.2M | cnt .6M | rowptr .6M | cursor .6M
    char* w = (char*)d_ws;
    int2*           edges  = (int2*)w;           w += (size_t)NNZ_E * 8;
    unsigned short* x0h    = (unsigned short*)w; w += (size_t)NTOT * DIM * 2;
    unsigned short* y1h    = (unsigned short*)w; w += (size_t)NTOT * DIM * 2;
    unsigned short* y2h    = (unsigned short*)w; w += (size_t)NTOT * DIM * 2;
    unsigned short* y3h    = (unsigned short*)w; w += (size_t)NTOT * DIM * 2;
    int*            cnt    = (int*)w;            w += (size_t)NTOT * 4;
    int*            rowptr = (int*)w;            w += (size_t)(NTOT + 1) * 4;
    int*            cursor = (int*)w;

    const int blk = 256;
    const int gElem = (TOT4 + blk - 1) / blk;                 // 9375
    const int gEdge = (NNZ_E + blk - 1) / blk;                // 18750
    const int gCnt  = (NTOT + blk - 1) / blk;                 // 586
    const int gRow  = (NTOT + (blk / 64) - 1) / (blk / 64);   // 37500 (4 waves/block)

    // CSR build
    zero_int<<<gCnt, blk, 0, stream>>>(cnt, NTOT);
    hist_kernel<<<gEdge, blk, 0, stream>>>(rows, cnt);
    scan_kernel<<<1, SCAN_T, 0, stream>>>(cnt, rowptr, cursor);
    scatter_kernel<<<gEdge, blk, 0, stream>>>(rows, cols, vals, cursor, edges);

    // Layer inputs in bf16
    convert_kernel<<<gElem, blk, 0, stream>>>(user, item, (ushort4*)x0h);

    // 3 propagation layers
    spmm_bf16<<<gRow, blk, 0, stream>>>(rowptr, edges, x0h, y1h);
    spmm_bf16<<<gRow, blk, 0, stream>>>(rowptr, edges, y1h, y2h);
    spmm_bf16<<<gRow, blk, 0, stream>>>(rowptr, edges, y2h, y3h);

    // Fused stage-mean
    final_kernel<<<gElem, blk, 0, stream>>>(user, item, (const ushort4*)y1h,
                                            (const ushort4*)y2h, (const ushort4*)y3h,
                                            (float4*)out);
}